// Round 9
// baseline (674.018 us; speedup 1.0000x reference)
//
#include <hip/hip_runtime.h>
#include <math.h>

#define BDIM 2
#define TDIM 2048
#define CDIM 2048
#define HDIM 16
#define DDIM 128
#define MDIM (BDIM*TDIM)   // 4096
#define N3   (3*CDIM)      // 6144

typedef __attribute__((ext_vector_type(8))) short short8;   // 8 bf16 = 4 VGPRs
typedef __attribute__((ext_vector_type(4))) float f32x4;

#define MFMA16(a, b, c) __builtin_amdgcn_mfma_f32_16x16x32_bf16((a), (b), (c), 0, 0, 0)

__device__ inline ushort f2b(float f) {                     // fp32 -> bf16 RNE
    unsigned u = __float_as_uint(f);
    unsigned r = (u + 0x7FFFu + ((u >> 16) & 1u)) >> 16;
    return (ushort)r;
}
__device__ inline float b2f(ushort h) { return __uint_as_float(((unsigned)h) << 16); }

// ---------------------------------------------------------------------------
// fp32 -> bf16 cast, 8 elems/thread
// ---------------------------------------------------------------------------
__global__ __launch_bounds__(256) void cast_bf16_kernel(const float* __restrict__ in,
                                                        ushort* __restrict__ out, size_t n)
{
    size_t i = ((size_t)blockIdx.x * 256 + threadIdx.x) * 8;
    if (i >= n) return;
    float4 a = *(const float4*)&in[i];
    float4 b = *(const float4*)&in[i + 4];
    ushort o[8] = { f2b(a.x), f2b(a.y), f2b(a.z), f2b(a.w),
                    f2b(b.x), f2b(b.y), f2b(b.z), f2b(b.w) };
    *(uint4*)&out[i] = *(uint4*)o;
}

// ---------------------------------------------------------------------------
// fp32 [R][C] -> bf16 [C][R] transpose+cast (32x32 LDS tile)
// ---------------------------------------------------------------------------
__global__ __launch_bounds__(256) void transpose_cast_kernel(const float* __restrict__ in,
                                                             ushort* __restrict__ out,
                                                             int R, int C)
{
    __shared__ float tile[32][33];
    const int c0 = blockIdx.x * 32, r0 = blockIdx.y * 32;
    const int tx = threadIdx.x & 31, ty = threadIdx.x >> 5;
    #pragma unroll
    for (int i = 0; i < 32; i += 8)
        tile[ty + i][tx] = in[(size_t)(r0 + ty + i) * C + c0 + tx];
    __syncthreads();
    #pragma unroll
    for (int i = 0; i < 32; i += 8)
        out[(size_t)(c0 + ty + i) * R + r0 + tx] = f2b(tile[tx][ty + i]);
}

// ---------------------------------------------------------------------------
// bf16 MFMA GEMM: C[M,N] = A[M,K] * Bt[N,K]^T. 128x128 tile, BK=32, 4 waves.
// ---------------------------------------------------------------------------
template<bool OUT_BF16>
__global__ __launch_bounds__(256) void gemm_bt_kernel(const ushort* __restrict__ A,
                                                      const ushort* __restrict__ Bt,
                                                      void* __restrict__ Cout,
                                                      int Mdim, int Ndim, int Kdim)
{
    __shared__ ushort Asm[128 * 32];   // [row][k] linear (global_load_lds dest)
    __shared__ ushort Bsm[128 * 32];   // [n][k]

    const int tid = threadIdx.x;
    const int l   = tid & 63;
    const int w   = tid >> 6;
    const int wm  = w >> 1, wn = w & 1;
    const int l15 = l & 15, lg = l >> 4;
    const int m0  = blockIdx.y * 128, n0 = blockIdx.x * 128;

    f32x4 acc[4][4];
    #pragma unroll
    for (int m = 0; m < 4; ++m)
        #pragma unroll
        for (int n = 0; n < 4; ++n) acc[m][n] = (f32x4){0.f, 0.f, 0.f, 0.f};

    for (int k0 = 0; k0 < Kdim; k0 += 32) {
        __syncthreads();                       // prior tile's readers done
        #pragma unroll
        for (int i = 0; i < 2; ++i) {          // 512 chunks x 16B per matrix
            const int c   = i * 256 + tid;
            const int row = c >> 2;
            const int k8  = (c & 3) << 3;
            __builtin_amdgcn_global_load_lds(
                (const __attribute__((address_space(1))) unsigned int*)(A + (size_t)(m0 + row) * Kdim + k0 + k8),
                (__attribute__((address_space(3))) unsigned int*)&Asm[c * 8], 16, 0, 0);
            __builtin_amdgcn_global_load_lds(
                (const __attribute__((address_space(1))) unsigned int*)(Bt + (size_t)(n0 + row) * Kdim + k0 + k8),
                (__attribute__((address_space(3))) unsigned int*)&Bsm[c * 8], 16, 0, 0);
        }
        __syncthreads();                       // drains vmcnt before barrier

        short8 af[4], bf[4];
        #pragma unroll
        for (int m = 0; m < 4; ++m)
            af[m] = *(const short8*)&Asm[(wm * 64 + m * 16 + l15) * 32 + lg * 8];
        #pragma unroll
        for (int n = 0; n < 4; ++n)
            bf[n] = *(const short8*)&Bsm[(wn * 64 + n * 16 + l15) * 32 + lg * 8];
        #pragma unroll
        for (int m = 0; m < 4; ++m)
            #pragma unroll
            for (int n = 0; n < 4; ++n)
                acc[m][n] = MFMA16(af[m], bf[n], acc[m][n]);
    }

    // C/D layout: col = l&15, row = (l>>4)*4 + r
    #pragma unroll
    for (int m = 0; m < 4; ++m)
        #pragma unroll
        for (int n = 0; n < 4; ++n)
            #pragma unroll
            for (int r = 0; r < 4; ++r) {
                const size_t row = m0 + wm * 64 + m * 16 + lg * 4 + r;
                const size_t col = n0 + wn * 64 + n * 16 + l15;
                if (OUT_BF16) ((ushort*)Cout)[row * Ndim + col] = f2b(acc[m][n][r]);
                else          ((float*) Cout)[row * Ndim + col] = acc[m][n][r];
            }
}

// ---------------------------------------------------------------------------
// RMSNorm + RoPE on bf16 q,k rows in place (fp32 math). Wave per 128-row.
// q additionally scaled by rsqrt(D)*log2(e) -> flash softmax runs in exp2 domain.
// ---------------------------------------------------------------------------
__global__ __launch_bounds__(256) void rmsrope_kernel(ushort* __restrict__ qkvb,
                                                      const int* __restrict__ segpos,
                                                      const float* __restrict__ q_scale,
                                                      const float* __restrict__ k_scale)
{
    const int row  = blockIdx.x * 4 + (threadIdx.x >> 6);  // [0, B*T*32)
    const int lane = threadIdx.x & 63;
    const int bt   = row >> 5;
    const int rem  = row & 31;
    const int isK  = rem >> 4;
    const int hh   = rem & 15;

    const float* scale = isK ? k_scale : q_scale;
    ushort* p = qkvb + (size_t)bt * N3 + isK * CDIM + hh * DDIM;

    float x1 = b2f(p[lane]);
    float x2 = b2f(p[lane + 64]);

    float ss = x1 * x1 + x2 * x2;
    #pragma unroll
    for (int off = 32; off > 0; off >>= 1) ss += __shfl_xor(ss, off, 64);
    const float inv = rsqrtf(ss * (1.0f / 128.0f) + 1e-6f);

    x1 = x1 * inv * (1.0f + scale[lane]);
    x2 = x2 * inv * (1.0f + scale[lane + 64]);

    const int   pos = segpos[bt];
    const float ts  = powf(10000.0f, (float)lane * (1.0f / 64.0f));
    const float ang = (float)pos / ts;
    const float sn = sinf(ang), cs = cosf(ang);

    float o1 = x1 * cs - x2 * sn;
    float o2 = x2 * cs + x1 * sn;
    if (!isK) {                       // rsqrt(128) * log2(e)
        o1 *= 0.1275174396f;
        o2 *= 0.1275174396f;
    }
    p[lane]      = f2b(o1);
    p[lane + 64] = f2b(o2);
}

// ---------------------------------------------------------------------------
// MFMA flash attention v2.
// Block = (128-q tile, b*h), 256 thr = 4 waves, wave owns 32 q rows (M_rep=2).
// KVBLK=64. Linear LDS + XOR swizzle (byte ^= (row&7)<<4) for Ks/Vt/Pw.
// K staged via global_load_lds with pre-swizzled SOURCE (linear dest).
// Softmax in exp2 domain (q pre-scaled by log2e), defer-max THR=8.
// ---------------------------------------------------------------------------
__global__ __launch_bounds__(256) void flash_kernel(const ushort* __restrict__ qkvb,
                                                    ushort* __restrict__ encb)
{
    __shared__ ushort Ks[64 * 128];      // [key][d]   16 KB, swizzled
    __shared__ ushort Vt[128 * 64];      // [d][key]   16 KB, swizzled
    __shared__ ushort Pw[4][32 * 64];    // per-wave [q][key] 16 KB, swizzled

    const int tid = threadIdx.x;
    const int l   = tid & 63;
    const int w   = tid >> 6;
    const int l15 = l & 15, lg = l >> 4;
    const int bh  = blockIdx.y;
    const int b   = bh >> 4, h = bh & 15;
    const int q0  = blockIdx.x * 128;

    const ushort* Qg    = qkvb + (size_t)(b * TDIM + q0 + w * 32) * N3 + h * DDIM;
    const ushort* Kbase = qkvb + (size_t)(b * TDIM) * N3 +     CDIM + h * DDIM;
    const ushort* Vbase = qkvb + (size_t)(b * TDIM) * N3 + 2 * CDIM + h * DDIM;

    // Q fragments in registers (A-operand: row=l&15, k=(l>>4)*8+e)
    short8 qf[2][4];
    #pragma unroll
    for (int m = 0; m < 2; ++m)
        #pragma unroll
        for (int kk = 0; kk < 4; ++kk)
            qf[m][kk] = *(const short8*)(Qg + (size_t)(m * 16 + l15) * N3 + kk * 32 + lg * 8);

    f32x4 acc[2][8];
    #pragma unroll
    for (int m = 0; m < 2; ++m)
        #pragma unroll
        for (int n = 0; n < 8; ++n) acc[m][n] = (f32x4){0.f, 0.f, 0.f, 0.f};
    float mprev[2][4], lrun[2][4];
    #pragma unroll
    for (int m = 0; m < 2; ++m)
        #pragma unroll
        for (int r = 0; r < 4; ++r) { mprev[m][r] = -1e30f; lrun[m][r] = 0.f; }

    for (int kt = 0; kt < TDIM; kt += 64) {
        // ---- V: global -> regs (no LDS side effects, issue before barrier)
        short8 vreg[4];
        #pragma unroll
        for (int i = 0; i < 4; ++i) {
            const int vd = (i * 4 + w) * 8;
            vreg[i] = *(const short8*)(Vbase + (size_t)(kt + l) * N3 + vd);
        }
        __syncthreads();                              // prev tile readers done

        // ---- K: global_load_lds, linear dest + pre-swizzled source
        #pragma unroll
        for (int i = 0; i < 4; ++i) {
            const int c    = i * 256 + tid;           // 16B chunk id, 0..1023
            const int row  = c >> 4;                  // key row
            const int bsw  = (c & 15) << 4;           // dest byte within row
            const int bsrc = bsw ^ ((row & 7) << 4);  // source byte (involution)
            __builtin_amdgcn_global_load_lds(
                (const __attribute__((address_space(1))) unsigned int*)(Kbase + (size_t)(kt + row) * N3 + (bsrc >> 1)),
                (__attribute__((address_space(3))) unsigned int*)&Ks[c * 8], 16, 0, 0);
        }
        // ---- V: regs -> LDS transposed, swizzled scalar writes
        #pragma unroll
        for (int i = 0; i < 4; ++i) {
            const int vd = (i * 4 + w) * 8;
            #pragma unroll
            for (int j = 0; j < 8; ++j) {
                const int d = vd + j;
                *(ushort*)((char*)Vt + d * 128 + (((l * 2) ^ ((d & 7) << 4)))) =
                    ((const ushort*)&vreg[i])[j];
            }
        }
        __syncthreads();                              // vmcnt drained by barrier

        // ---- S = Q K^T : 32q x 64k per wave (2 M-reps x 4 key-frags)
        f32x4 sf[2][4];
        #pragma unroll
        for (int m = 0; m < 2; ++m)
            #pragma unroll
            for (int n = 0; n < 4; ++n) sf[m][n] = (f32x4){0.f, 0.f, 0.f, 0.f};
        #pragma unroll
        for (int n = 0; n < 4; ++n) {
            const int key = n * 16 + l15;
            #pragma unroll
            for (int kk = 0; kk < 4; ++kk) {
                short8 kf = *(const short8*)((const char*)Ks + key * 256 +
                                             (((kk * 64 + lg * 16) ^ ((key & 7) << 4))));
                sf[0][n] = MFMA16(qf[0][kk], kf, sf[0][n]);
                sf[1][n] = MFMA16(qf[1][kk], kf, sf[1][n]);
            }
        }

        // ---- online softmax (exp2 domain), defer-max THR=8
        #pragma unroll
        for (int m = 0; m < 2; ++m)
            #pragma unroll
            for (int r = 0; r < 4; ++r) {
                float rm = fmaxf(fmaxf(sf[m][0][r], sf[m][1][r]),
                                 fmaxf(sf[m][2][r], sf[m][3][r]));
                #pragma unroll
                for (int off = 8; off > 0; off >>= 1)
                    rm = fmaxf(rm, __shfl_xor(rm, off, 16));
                if (rm > mprev[m][r] + 8.0f) {        // rescale only on real growth
                    const float sc = exp2f(mprev[m][r] - rm);
                    mprev[m][r] = rm;
                    lrun[m][r] *= sc;
                    #pragma unroll
                    for (int n = 0; n < 8; ++n) acc[m][n][r] *= sc;
                }
                const float mn = mprev[m][r];
                float rs = 0.f;
                const int qr = m * 16 + lg * 4 + r;
                #pragma unroll
                for (int n = 0; n < 4; ++n) {
                    const float pv = exp2f(sf[m][n][r] - mn);   // <= 2^8
                    rs += pv;
                    *(ushort*)((char*)&Pw[w][0] + qr * 128 +
                               ((n * 32 + l15 * 2) ^ ((qr & 7) << 4))) = f2b(pv);
                }
                #pragma unroll
                for (int off = 8; off > 0; off >>= 1) rs += __shfl_xor(rs, off, 16);
                lrun[m][r] += rs;
            }

        // ---- O += P V (P wave-local; no barrier needed)
        short8 pf[2][2];
        #pragma unroll
        for (int m = 0; m < 2; ++m)
            #pragma unroll
            for (int kk = 0; kk < 2; ++kk) {
                const int qr = m * 16 + l15;
                pf[m][kk] = *(const short8*)((const char*)&Pw[w][0] + qr * 128 +
                                             (((kk * 64 + lg * 16) ^ ((qr & 7) << 4))));
            }
        #pragma unroll
        for (int n = 0; n < 8; ++n) {
            const int d = n * 16 + l15;
            #pragma unroll
            for (int kk = 0; kk < 2; ++kk) {
                short8 vf = *(const short8*)((const char*)Vt + d * 128 +
                                             (((kk * 64 + lg * 16) ^ ((d & 7) << 4))));
                acc[0][n] = MFMA16(pf[0][kk], vf, acc[0][n]);
                acc[1][n] = MFMA16(pf[1][kk], vf, acc[1][n]);
            }
        }
    }

    #pragma unroll
    for (int m = 0; m < 2; ++m)
        #pragma unroll
        for (int r = 0; r < 4; ++r) {
            const float inv = 1.0f / lrun[m][r];
            const size_t row = (size_t)(b * TDIM + q0 + w * 32 + m * 16 + lg * 4 + r);
            #pragma unroll
            for (int n = 0; n < 8; ++n)
                encb[row * CDIM + h * DDIM + n * 16 + l15] = f2b(acc[m][n][r] * inv);
        }
}

// ---------------------------------------------------------------------------
extern "C" void kernel_launch(void* const* d_in, const int* in_sizes, int n_in,
                              void* d_out, int out_size, void* d_ws, size_t ws_size,
                              hipStream_t stream)
{
    const float* x       = (const float*)d_in[0];
    const int*   segpos  = (const int*)  d_in[1];
    // d_in[2] = attn_mask (all true) -> unused
    const float* w_qkv   = (const float*)d_in[3];
    const float* w_out   = (const float*)d_in[4];
    const float* q_scale = (const float*)d_in[5];
    const float* k_scale = (const float*)d_in[6];
    float*       out     = (float*)d_out;

    // workspace layout (bf16 = ushort), total 112 MB
    ushort* x_b    = (ushort*)d_ws;                          // [4096][2048]
    ushort* wqkvT  = x_b   + (size_t)MDIM * CDIM;            // [6144][2048]
    ushort* woutT  = wqkvT + (size_t)N3   * CDIM;            // [2048][2048]
    ushort* qkv_b  = woutT + (size_t)CDIM * CDIM;            // [4096][6144]
    ushort* enc_b  = qkv_b + (size_t)MDIM * N3;              // [4096][2048]

    // 1) casts / weight transposes
    cast_bf16_kernel<<<dim3((MDIM * CDIM) / (256 * 8)), 256, 0, stream>>>(x, x_b, (size_t)MDIM * CDIM);
    transpose_cast_kernel<<<dim3(N3 / 32, CDIM / 32), 256, 0, stream>>>(w_qkv, wqkvT, CDIM, N3);
    transpose_cast_kernel<<<dim3(CDIM / 32, CDIM / 32), 256, 0, stream>>>(w_out, woutT, CDIM, CDIM);

    // 2) qkv = x @ w_qkv   (bf16 out)
    gemm_bt_kernel<true><<<dim3(N3 / 128, MDIM / 128), 256, 0, stream>>>(x_b, wqkvT, qkv_b, MDIM, N3, CDIM);

    // 3) RMSNorm + RoPE in place on q,k (q also picks up log2e)
    rmsrope_kernel<<<dim3(MDIM * 32 / 4), 256, 0, stream>>>(qkv_b, segpos, q_scale, k_scale);

    // 4) flash attention -> enc_b (bf16)
    flash_kernel<<<dim3(TDIM / 128, BDIM * HDIM), 256, 0, stream>>>(qkv_b, enc_b);

    // 5) out = enc @ w_out (fp32 out)
    gemm_bt_kernel<false><<<dim3(CDIM / 128, MDIM / 128), 256, 0, stream>>>(enc_b, woutT, out, MDIM, CDIM, CDIM);
}

// Round 10
// 539.951 us; speedup vs baseline: 1.2483x; 1.2483x over previous
//
#include <hip/hip_runtime.h>
#include <math.h>

#define BDIM 2
#define TDIM 2048
#define CDIM 2048
#define HDIM 16
#define DDIM 128
#define MDIM (BDIM*TDIM)   // 4096
#define N3   (3*CDIM)      // 6144

typedef __attribute__((ext_vector_type(8))) short short8;   // 8 bf16 = 4 VGPRs
typedef __attribute__((ext_vector_type(4))) float f32x4;

#define MFMA16(a, b, c) __builtin_amdgcn_mfma_f32_16x16x32_bf16((a), (b), (c), 0, 0, 0)

__device__ inline ushort f2b(float f) {                     // fp32 -> bf16 RNE
    unsigned u = __float_as_uint(f);
    unsigned r = (u + 0x7FFFu + ((u >> 16) & 1u)) >> 16;
    return (ushort)r;
}
__device__ inline float b2f(ushort h) { return __uint_as_float(((unsigned)h) << 16); }

// ---------------------------------------------------------------------------
// fp32 -> bf16 cast, 8 elems/thread
// ---------------------------------------------------------------------------
__global__ __launch_bounds__(256) void cast_bf16_kernel(const float* __restrict__ in,
                                                        ushort* __restrict__ out, size_t n)
{
    size_t i = ((size_t)blockIdx.x * 256 + threadIdx.x) * 8;
    if (i >= n) return;
    float4 a = *(const float4*)&in[i];
    float4 b = *(const float4*)&in[i + 4];
    ushort o[8] = { f2b(a.x), f2b(a.y), f2b(a.z), f2b(a.w),
                    f2b(b.x), f2b(b.y), f2b(b.z), f2b(b.w) };
    *(uint4*)&out[i] = *(uint4*)o;
}

// ---------------------------------------------------------------------------
// fp32 [R][C] -> bf16 [C][R] transpose+cast (32x32 LDS tile)
// ---------------------------------------------------------------------------
__global__ __launch_bounds__(256) void transpose_cast_kernel(const float* __restrict__ in,
                                                             ushort* __restrict__ out,
                                                             int R, int C)
{
    __shared__ float tile[32][33];
    const int c0 = blockIdx.x * 32, r0 = blockIdx.y * 32;
    const int tx = threadIdx.x & 31, ty = threadIdx.x >> 5;
    #pragma unroll
    for (int i = 0; i < 32; i += 8)
        tile[ty + i][tx] = in[(size_t)(r0 + ty + i) * C + c0 + tx];
    __syncthreads();
    #pragma unroll
    for (int i = 0; i < 32; i += 8)
        out[(size_t)(c0 + ty + i) * R + r0 + tx] = f2b(tile[tx][ty + i]);
}

// ---------------------------------------------------------------------------
// bf16 MFMA GEMM: C[M,N] = A[M,K] * Bt[N,K]^T. 128x128 tile, BK=32, 4 waves.
// ---------------------------------------------------------------------------
template<bool OUT_BF16>
__global__ __launch_bounds__(256) void gemm_bt_kernel(const ushort* __restrict__ A,
                                                      const ushort* __restrict__ Bt,
                                                      void* __restrict__ Cout,
                                                      int Mdim, int Ndim, int Kdim)
{
    __shared__ ushort Asm[128 * 32];   // [row][k] linear (global_load_lds dest)
    __shared__ ushort Bsm[128 * 32];   // [n][k]

    const int tid = threadIdx.x;
    const int l   = tid & 63;
    const int w   = tid >> 6;
    const int wm  = w >> 1, wn = w & 1;
    const int l15 = l & 15, lg = l >> 4;
    const int m0  = blockIdx.y * 128, n0 = blockIdx.x * 128;

    f32x4 acc[4][4];
    #pragma unroll
    for (int m = 0; m < 4; ++m)
        #pragma unroll
        for (int n = 0; n < 4; ++n) acc[m][n] = (f32x4){0.f, 0.f, 0.f, 0.f};

    for (int k0 = 0; k0 < Kdim; k0 += 32) {
        __syncthreads();                       // prior tile's readers done
        #pragma unroll
        for (int i = 0; i < 2; ++i) {          // 512 chunks x 16B per matrix
            const int c   = i * 256 + tid;
            const int row = c >> 2;
            const int k8  = (c & 3) << 3;
            __builtin_amdgcn_global_load_lds(
                (const __attribute__((address_space(1))) unsigned int*)(A + (size_t)(m0 + row) * Kdim + k0 + k8),
                (__attribute__((address_space(3))) unsigned int*)&Asm[c * 8], 16, 0, 0);
            __builtin_amdgcn_global_load_lds(
                (const __attribute__((address_space(1))) unsigned int*)(Bt + (size_t)(n0 + row) * Kdim + k0 + k8),
                (__attribute__((address_space(3))) unsigned int*)&Bsm[c * 8], 16, 0, 0);
        }
        __syncthreads();                       // drains vmcnt before barrier

        short8 af[4], bf[4];
        #pragma unroll
        for (int m = 0; m < 4; ++m)
            af[m] = *(const short8*)&Asm[(wm * 64 + m * 16 + l15) * 32 + lg * 8];
        #pragma unroll
        for (int n = 0; n < 4; ++n)
            bf[n] = *(const short8*)&Bsm[(wn * 64 + n * 16 + l15) * 32 + lg * 8];
        #pragma unroll
        for (int m = 0; m < 4; ++m)
            #pragma unroll
            for (int n = 0; n < 4; ++n)
                acc[m][n] = MFMA16(af[m], bf[n], acc[m][n]);
    }

    // C/D layout: col = l&15, row = (l>>4)*4 + r
    #pragma unroll
    for (int m = 0; m < 4; ++m)
        #pragma unroll
        for (int n = 0; n < 4; ++n)
            #pragma unroll
            for (int r = 0; r < 4; ++r) {
                const size_t row = m0 + wm * 64 + m * 16 + lg * 4 + r;
                const size_t col = n0 + wn * 64 + n * 16 + l15;
                if (OUT_BF16) ((ushort*)Cout)[row * Ndim + col] = f2b(acc[m][n][r]);
                else          ((float*) Cout)[row * Ndim + col] = acc[m][n][r];
            }
}

// ---------------------------------------------------------------------------
// RMSNorm + RoPE on bf16 q,k rows in place (fp32 math). Wave per 128-row.
// q additionally scaled by rsqrt(D)*log2(e) -> flash softmax runs in exp2 domain.
// ---------------------------------------------------------------------------
__global__ __launch_bounds__(256) void rmsrope_kernel(ushort* __restrict__ qkvb,
                                                      const int* __restrict__ segpos,
                                                      const float* __restrict__ q_scale,
                                                      const float* __restrict__ k_scale)
{
    const int row  = blockIdx.x * 4 + (threadIdx.x >> 6);  // [0, B*T*32)
    const int lane = threadIdx.x & 63;
    const int bt   = row >> 5;
    const int rem  = row & 31;
    const int isK  = rem >> 4;
    const int hh   = rem & 15;

    const float* scale = isK ? k_scale : q_scale;
    ushort* p = qkvb + (size_t)bt * N3 + isK * CDIM + hh * DDIM;

    float x1 = b2f(p[lane]);
    float x2 = b2f(p[lane + 64]);

    float ss = x1 * x1 + x2 * x2;
    #pragma unroll
    for (int off = 32; off > 0; off >>= 1) ss += __shfl_xor(ss, off, 64);
    const float inv = rsqrtf(ss * (1.0f / 128.0f) + 1e-6f);

    x1 = x1 * inv * (1.0f + scale[lane]);
    x2 = x2 * inv * (1.0f + scale[lane + 64]);

    const int   pos = segpos[bt];
    const float ts  = powf(10000.0f, (float)lane * (1.0f / 64.0f));
    const float ang = (float)pos / ts;
    const float sn = sinf(ang), cs = cosf(ang);

    float o1 = x1 * cs - x2 * sn;
    float o2 = x2 * cs + x1 * sn;
    if (!isK) {                       // rsqrt(128) * log2(e)
        o1 *= 0.1275174396f;
        o2 *= 0.1275174396f;
    }
    p[lane]      = f2b(o1);
    p[lane + 64] = f2b(o2);
}

// ---------------------------------------------------------------------------
// MFMA flash attention v3.
// Block = (128-q tile, b*h), 512 thr = 8 waves, wave owns 16 q rows (M_rep=1).
// KVBLK=64. Linear LDS + XOR swizzle (byte ^= (row&7)<<4) for Ks/Vt/Pw.
// K staged via global_load_lds with pre-swizzled SOURCE (linear dest).
// Softmax in exp2 domain (q pre-scaled by log2e), defer-max THR=8.
// v3 vs v2: M_rep 2->1 with 8 waves, restoring VGPR<=128 and 16 waves/CU
// (v2's 152 VGPR + 512-block grid collapsed occupancy to 11.6%).
// ---------------------------------------------------------------------------
__global__ __launch_bounds__(512, 4) void flash_kernel(const ushort* __restrict__ qkvb,
                                                       ushort* __restrict__ encb)
{
    __shared__ ushort Ks[64 * 128];      // [key][d]   16 KB, swizzled
    __shared__ ushort Vt[128 * 64];      // [d][key]   16 KB, swizzled
    __shared__ ushort Pw[8][16 * 64];    // per-wave P [q][key] 16 KB, swizzled

    const int tid = threadIdx.x;
    const int l   = tid & 63;
    const int w   = tid >> 6;            // wave 0..7
    const int l15 = l & 15, lg = l >> 4;
    const int bh  = blockIdx.y;
    const int b   = bh >> 4, h = bh & 15;
    const int q0  = blockIdx.x * 128;

    const ushort* Qg    = qkvb + (size_t)(b * TDIM + q0 + w * 16 + l15) * N3 + h * DDIM;
    const ushort* Kbase = qkvb + (size_t)(b * TDIM) * N3 +     CDIM + h * DDIM;
    const ushort* Vbase = qkvb + (size_t)(b * TDIM) * N3 + 2 * CDIM + h * DDIM;

    // Q fragments in registers (A-operand: row=l&15, k=(l>>4)*8+e)
    short8 qf[4];
    #pragma unroll
    for (int kk = 0; kk < 4; ++kk)
        qf[kk] = *(const short8*)(Qg + kk * 32 + lg * 8);

    f32x4 acc[8];
    #pragma unroll
    for (int n = 0; n < 8; ++n) acc[n] = (f32x4){0.f, 0.f, 0.f, 0.f};
    float mprev[4] = {-1e30f, -1e30f, -1e30f, -1e30f};
    float lrun[4]  = {0.f, 0.f, 0.f, 0.f};

    for (int kt = 0; kt < TDIM; kt += 64) {
        // ---- V: global -> regs (no LDS side effects, issue before barrier)
        short8 vreg[2];
        #pragma unroll
        for (int i = 0; i < 2; ++i)
            vreg[i] = *(const short8*)(Vbase + (size_t)(kt + l) * N3 + w * 16 + i * 8);
        __syncthreads();                              // prev tile readers done

        // ---- K: global_load_lds, linear dest + pre-swizzled source
        #pragma unroll
        for (int i = 0; i < 2; ++i) {
            const int c    = i * 512 + tid;           // 16B chunk id, 0..1023
            const int row  = c >> 4;                  // key row
            const int bsw  = (c & 15) << 4;           // dest byte within row
            const int bsrc = bsw ^ ((row & 7) << 4);  // source byte (involution)
            __builtin_amdgcn_global_load_lds(
                (const __attribute__((address_space(1))) unsigned int*)(Kbase + (size_t)(kt + row) * N3 + (bsrc >> 1)),
                (__attribute__((address_space(3))) unsigned int*)&Ks[c * 8], 16, 0, 0);
        }
        // ---- V: regs -> LDS transposed, swizzled scalar writes
        #pragma unroll
        for (int i = 0; i < 2; ++i) {
            #pragma unroll
            for (int j = 0; j < 8; ++j) {
                const int d = w * 16 + i * 8 + j;
                *(ushort*)((char*)Vt + d * 128 + (((l * 2) ^ ((d & 7) << 4)))) =
                    ((const ushort*)&vreg[i])[j];
            }
        }
        __syncthreads();                              // vmcnt drained by barrier

        // ---- S = Q K^T : 16q x 64k per wave (4 key-frags)
        f32x4 sf[4];
        #pragma unroll
        for (int n = 0; n < 4; ++n) sf[n] = (f32x4){0.f, 0.f, 0.f, 0.f};
        #pragma unroll
        for (int n = 0; n < 4; ++n) {
            const int key = n * 16 + l15;
            #pragma unroll
            for (int kk = 0; kk < 4; ++kk) {
                short8 kf = *(const short8*)((const char*)Ks + key * 256 +
                                             (((kk * 64 + lg * 16) ^ ((key & 7) << 4))));
                sf[n] = MFMA16(qf[kk], kf, sf[n]);
            }
        }

        // ---- online softmax (exp2 domain), defer-max THR=8
        #pragma unroll
        for (int r = 0; r < 4; ++r) {
            float rm = fmaxf(fmaxf(sf[0][r], sf[1][r]), fmaxf(sf[2][r], sf[3][r]));
            #pragma unroll
            for (int off = 8; off > 0; off >>= 1)
                rm = fmaxf(rm, __shfl_xor(rm, off, 16));
            if (rm > mprev[r] + 8.0f) {               // rescale only on real growth
                const float sc = exp2f(mprev[r] - rm);
                mprev[r] = rm;
                lrun[r] *= sc;
                #pragma unroll
                for (int n = 0; n < 8; ++n) acc[n][r] *= sc;
            }
            const float mn = mprev[r];
            float rs = 0.f;
            const int qr = lg * 4 + r;
            #pragma unroll
            for (int n = 0; n < 4; ++n) {
                const float pv = exp2f(sf[n][r] - mn);   // <= 2^8
                rs += pv;
                *(ushort*)((char*)&Pw[w][0] + qr * 128 +
                           ((n * 32 + l15 * 2) ^ ((qr & 7) << 4))) = f2b(pv);
            }
            #pragma unroll
            for (int off = 8; off > 0; off >>= 1) rs += __shfl_xor(rs, off, 16);
            lrun[r] += rs;
        }

        // ---- O += P V (P wave-local; no barrier needed)
        short8 pf[2];
        #pragma unroll
        for (int kk = 0; kk < 2; ++kk) {
            const int qr = l15;
            pf[kk] = *(const short8*)((const char*)&Pw[w][0] + qr * 128 +
                                      (((kk * 64 + lg * 16) ^ ((qr & 7) << 4))));
        }
        #pragma unroll
        for (int n = 0; n < 8; ++n) {
            const int d = n * 16 + l15;
            #pragma unroll
            for (int kk = 0; kk < 2; ++kk) {
                short8 vf = *(const short8*)((const char*)Vt + d * 128 +
                                             (((kk * 64 + lg * 16) ^ ((d & 7) << 4))));
                acc[n] = MFMA16(pf[kk], vf, acc[n]);
            }
        }
    }

    #pragma unroll
    for (int r = 0; r < 4; ++r) {
        const float inv = 1.0f / lrun[r];
        const size_t row = (size_t)(b * TDIM + q0 + w * 16 + lg * 4 + r);
        #pragma unroll
        for (int n = 0; n < 8; ++n)
            encb[row * CDIM + h * DDIM + n * 16 + l15] = f2b(acc[n][r] * inv);
    }
}

// ---------------------------------------------------------------------------
extern "C" void kernel_launch(void* const* d_in, const int* in_sizes, int n_in,
                              void* d_out, int out_size, void* d_ws, size_t ws_size,
                              hipStream_t stream)
{
    const float* x       = (const float*)d_in[0];
    const int*   segpos  = (const int*)  d_in[1];
    // d_in[2] = attn_mask (all true) -> unused
    const float* w_qkv   = (const float*)d_in[3];
    const float* w_out   = (const float*)d_in[4];
    const float* q_scale = (const float*)d_in[5];
    const float* k_scale = (const float*)d_in[6];
    float*       out     = (float*)d_out;

    // workspace layout (bf16 = ushort), total 112 MB
    ushort* x_b    = (ushort*)d_ws;                          // [4096][2048]
    ushort* wqkvT  = x_b   + (size_t)MDIM * CDIM;            // [6144][2048]
    ushort* woutT  = wqkvT + (size_t)N3   * CDIM;            // [2048][2048]
    ushort* qkv_b  = woutT + (size_t)CDIM * CDIM;            // [4096][6144]
    ushort* enc_b  = qkv_b + (size_t)MDIM * N3;              // [4096][2048]

    // 1) casts / weight transposes
    cast_bf16_kernel<<<dim3((MDIM * CDIM) / (256 * 8)), 256, 0, stream>>>(x, x_b, (size_t)MDIM * CDIM);
    transpose_cast_kernel<<<dim3(N3 / 32, CDIM / 32), 256, 0, stream>>>(w_qkv, wqkvT, CDIM, N3);
    transpose_cast_kernel<<<dim3(CDIM / 32, CDIM / 32), 256, 0, stream>>>(w_out, woutT, CDIM, CDIM);

    // 2) qkv = x @ w_qkv   (bf16 out)
    gemm_bt_kernel<true><<<dim3(N3 / 128, MDIM / 128), 256, 0, stream>>>(x_b, wqkvT, qkv_b, MDIM, N3, CDIM);

    // 3) RMSNorm + RoPE in place on q,k (q also picks up log2e)
    rmsrope_kernel<<<dim3(MDIM * 32 / 4), 256, 0, stream>>>(qkv_b, segpos, q_scale, k_scale);

    // 4) flash attention -> enc_b (bf16)
    flash_kernel<<<dim3(TDIM / 128, BDIM * HDIM), 512, 0, stream>>>(qkv_b, enc_b);

    // 5) out = enc @ w_out (fp32 out)
    gemm_bt_kernel<false><<<dim3(CDIM / 128, MDIM / 128), 256, 0, stream>>>(enc_b, woutT, out, MDIM, CDIM, CDIM);
}

// Round 13
// 527.666 us; speedup vs baseline: 1.2774x; 1.0233x over previous
//
#include <hip/hip_runtime.h>
#include <math.h>

#define BDIM 2
#define TDIM 2048
#define CDIM 2048
#define HDIM 16
#define DDIM 128
#define MDIM (BDIM*TDIM)   // 4096
#define N3   (3*CDIM)      // 6144

typedef __attribute__((ext_vector_type(8))) short short8;   // 8 bf16 = 4 VGPRs
typedef __attribute__((ext_vector_type(4))) float f32x4;

#define MFMA16(a, b, c) __builtin_amdgcn_mfma_f32_16x16x32_bf16((a), (b), (c), 0, 0, 0)

__device__ inline ushort f2b(float f) {                     // fp32 -> bf16 RNE
    unsigned u = __float_as_uint(f);
    unsigned r = (u + 0x7FFFu + ((u >> 16) & 1u)) >> 16;
    return (ushort)r;
}
__device__ inline float b2f(ushort h) { return __uint_as_float(((unsigned)h) << 16); }

// ---------------------------------------------------------------------------
// fp32 -> bf16 cast, 8 elems/thread
// ---------------------------------------------------------------------------
__global__ __launch_bounds__(256) void cast_bf16_kernel(const float* __restrict__ in,
                                                        ushort* __restrict__ out, size_t n)
{
    size_t i = ((size_t)blockIdx.x * 256 + threadIdx.x) * 8;
    if (i >= n) return;
    float4 a = *(const float4*)&in[i];
    float4 b = *(const float4*)&in[i + 4];
    ushort o[8] = { f2b(a.x), f2b(a.y), f2b(a.z), f2b(a.w),
                    f2b(b.x), f2b(b.y), f2b(b.z), f2b(b.w) };
    *(uint4*)&out[i] = *(uint4*)o;
}

// ---------------------------------------------------------------------------
// fp32 [R][C] -> bf16 [C][R] transpose+cast (32x32 LDS tile)
// ---------------------------------------------------------------------------
__global__ __launch_bounds__(256) void transpose_cast_kernel(const float* __restrict__ in,
                                                             ushort* __restrict__ out,
                                                             int R, int C)
{
    __shared__ float tile[32][33];
    const int c0 = blockIdx.x * 32, r0 = blockIdx.y * 32;
    const int tx = threadIdx.x & 31, ty = threadIdx.x >> 5;
    #pragma unroll
    for (int i = 0; i < 32; i += 8)
        tile[ty + i][tx] = in[(size_t)(r0 + ty + i) * C + c0 + tx];
    __syncthreads();
    #pragma unroll
    for (int i = 0; i < 32; i += 8)
        out[(size_t)(c0 + ty + i) * R + r0 + tx] = f2b(tile[tx][ty + i]);
}

// ---------------------------------------------------------------------------
// 8-phase 256x256 bf16 MFMA GEMM (T2+T3+T4+T5): C[M,N] = A[M,K] * Bt[N,K]^T.
// BK=64, 512 thr = 8 waves (2M x 4N), per-wave C = 128x64 (acc 8x4 f32x4).
// Double-buffered 128 KiB LDS, XOR-swizzle byte^=(row&7)<<4 (both sides),
// per-tile 4 phases {ds_read quad | 1 half-tile gload_lds | bar | lgkm0 |
// setprio MFMA | bar}, counted vmcnt(4) at tile boundary (0 only at tail).
// Staging plan per tile tc: phases A/B stage A(tc+1) halves (A(tc) reads done
// by phase C), phases C/D stage B(tc+2) halves (B(tc) reads done by phase B).
// At phase D 12 loads in flight; vmcnt(4) forces all 8 of tile tc+1 landed.
// ---------------------------------------------------------------------------
template<bool OUT_BF16>
__global__ __launch_bounds__(512, 2) void gemm256_kernel(const ushort* __restrict__ A,
                                                         const ushort* __restrict__ Bt,
                                                         void* __restrict__ Cout,
                                                         int Ndim, int Kdim)
{
    __shared__ ushort SMEM[2][2][256 * 64];   // [buf][A=0/B=1][row*64+k], 128 KiB

    const int tid = threadIdx.x;
    const int l   = tid & 63;
    const int w   = tid >> 6;
    const int wm  = w >> 2, wn = w & 3;
    const int l15 = l & 15, lg = l >> 4;
    const int m0  = blockIdx.y * 256, n0 = blockIdx.x * 256;
    const int nt  = Kdim >> 6;                // K tiles of 64

    f32x4 acc[8][4];
    #pragma unroll
    for (int m = 0; m < 8; ++m)
        #pragma unroll
        for (int n = 0; n < 4; ++n) acc[m][n] = (f32x4){0.f, 0.f, 0.f, 0.f};

    // stage one half-tile (128 rows x 64 k) of matrix mat for K-tile tt.
    // Linear LDS dest (wave-uniform + lane*16), inverse-swizzled global source.
    auto stage = [&](const ushort* __restrict__ src, int mat, int blk0, int tt, int h) {
        if (tt >= nt) return;
        #pragma unroll
        for (int j = 0; j < 2; ++j) {
            const int ch  = (j << 9) + tid;                    // 0..1023
            const int row = ch >> 3;                           // 0..127 within half
            const int cb  = ((ch & 7) << 4) ^ ((row & 7) << 4);// src byte-in-row
            __builtin_amdgcn_global_load_lds(
                (const __attribute__((address_space(1))) unsigned int*)
                    (src + (size_t)(blk0 + h * 128 + row) * Kdim + tt * 64 + (cb >> 1)),
                (__attribute__((address_space(3))) unsigned int*)
                    (&SMEM[tt & 1][mat][h * 8192 + ch * 8]),
                16, 0, 0);
        }
    };
    // swizzled fragment reads (A-operand: row=l15-based, k = kc*32 + lg*8 + e)
    auto lda = [&](int buf, int m, int kc) -> short8 {
        const int row = wm * 128 + m * 16 + l15;
        const int cb  = (kc * 64 + lg * 16) ^ ((row & 7) << 4);
        return *(const short8*)((const char*)&SMEM[buf][0][0] + row * 128 + cb);
    };
    auto ldb = [&](int buf, int n, int kc) -> short8 {
        const int row = wn * 64 + n * 16 + l15;
        const int cb  = (kc * 64 + lg * 16) ^ ((row & 7) << 4);
        return *(const short8*)((const char*)&SMEM[buf][1][0] + row * 128 + cb);
    };

    short8 aA[4][2], aB[4][2];

#define GBAR() __builtin_amdgcn_s_barrier()
#define LGKM0() do { asm volatile("s_waitcnt lgkmcnt(0)" ::: "memory"); \
                     __builtin_amdgcn_sched_barrier(0); } while (0)
#define QUAD(mh, nh)                                                             \
    do {                                                                         \
        __builtin_amdgcn_s_setprio(1);                                           \
        _Pragma("unroll")                                                        \
        for (int mi = 0; mi < 4; ++mi)                                           \
            _Pragma("unroll")                                                    \
            for (int ni = 0; ni < 2; ++ni)                                       \
                _Pragma("unroll")                                                \
                for (int kc = 0; kc < 2; ++kc)                                   \
                    acc[(mh)*4+mi][(nh)*2+ni] =                                  \
                        MFMA16(aA[mi][kc], aB[(nh)*2+ni][kc],                    \
                               acc[(mh)*4+mi][(nh)*2+ni]);                       \
        __builtin_amdgcn_s_setprio(0);                                           \
    } while (0)

    // prologue: tile 0 fully + tile 1's B halves (12 loads); wait tile 0 (8 oldest).
    stage(A,  0, m0, 0, 0); stage(A,  0, m0, 0, 1);
    stage(Bt, 1, n0, 0, 0); stage(Bt, 1, n0, 0, 1);
    stage(Bt, 1, n0, 1, 0); stage(Bt, 1, n0, 1, 1);
    asm volatile("s_waitcnt vmcnt(4)" ::: "memory");
    GBAR();

    for (int tc = 0; tc < nt; ++tc) {
        const int buf = tc & 1;
        // ---- phase A: quad (0,0); reads A0-3 + B0-1; stage A(tc+1) half0
        #pragma unroll
        for (int mi = 0; mi < 4; ++mi) { aA[mi][0] = lda(buf, mi, 0); aA[mi][1] = lda(buf, mi, 1); }
        #pragma unroll
        for (int ni = 0; ni < 2; ++ni) { aB[ni][0] = ldb(buf, ni, 0); aB[ni][1] = ldb(buf, ni, 1); }
        stage(A, 0, m0, tc + 1, 0);
        GBAR(); LGKM0();
        QUAD(0, 0);
        GBAR();
        // ---- phase B: quad (0,1); reads B2-3; stage A(tc+1) half1
        #pragma unroll
        for (int ni = 2; ni < 4; ++ni) { aB[ni][0] = ldb(buf, ni, 0); aB[ni][1] = ldb(buf, ni, 1); }
        stage(A, 0, m0, tc + 1, 1);
        GBAR(); LGKM0();
        QUAD(0, 1);
        GBAR();
        // ---- phase C: quad (1,0); reads A4-7; stage B(tc+2) half0
        #pragma unroll
        for (int mi = 0; mi < 4; ++mi) { aA[mi][0] = lda(buf, 4 + mi, 0); aA[mi][1] = lda(buf, 4 + mi, 1); }
        stage(Bt, 1, n0, tc + 2, 0);
        GBAR(); LGKM0();
        QUAD(1, 0);
        GBAR();
        // ---- phase D: quad (1,1); stage B(tc+2) half1; counted vmcnt at boundary
        stage(Bt, 1, n0, tc + 2, 1);
        if (tc + 2 < nt) { asm volatile("s_waitcnt vmcnt(4)" ::: "memory"); }
        else             { asm volatile("s_waitcnt vmcnt(0)" ::: "memory"); }
        GBAR();
        QUAD(1, 1);
        GBAR();
    }

    // C/D layout: col = l15, row = lg*4 + r
    #pragma unroll
    for (int m = 0; m < 8; ++m)
        #pragma unroll
        for (int n = 0; n < 4; ++n)
            #pragma unroll
            for (int r = 0; r < 4; ++r) {
                const size_t row = m0 + wm * 128 + m * 16 + lg * 4 + r;
                const size_t col = n0 + wn * 64 + n * 16 + l15;
                if (OUT_BF16) ((ushort*)Cout)[row * Ndim + col] = f2b(acc[m][n][r]);
                else          ((float*) Cout)[row * Ndim + col] = acc[m][n][r];
            }
#undef QUAD
#undef LGKM0
#undef GBAR
}

// ---------------------------------------------------------------------------
// RMSNorm + RoPE on bf16 q,k rows in place (fp32 math). Wave per 128-row.
// q additionally scaled by rsqrt(D)*log2(e) -> flash softmax runs in exp2 domain.
// ---------------------------------------------------------------------------
__global__ __launch_bounds__(256) void rmsrope_kernel(ushort* __restrict__ qkvb,
                                                      const int* __restrict__ segpos,
                                                      const float* __restrict__ q_scale,
                                                      const float* __restrict__ k_scale)
{
    const int row  = blockIdx.x * 4 + (threadIdx.x >> 6);  // [0, B*T*32)
    const int lane = threadIdx.x & 63;
    const int bt   = row >> 5;
    const int rem  = row & 31;
    const int isK  = rem >> 4;
    const int hh   = rem & 15;

    const float* scale = isK ? k_scale : q_scale;
    ushort* p = qkvb + (size_t)bt * N3 + isK * CDIM + hh * DDIM;

    float x1 = b2f(p[lane]);
    float x2 = b2f(p[lane + 64]);

    float ss = x1 * x1 + x2 * x2;
    #pragma unroll
    for (int off = 32; off > 0; off >>= 1) ss += __shfl_xor(ss, off, 64);
    const float inv = rsqrtf(ss * (1.0f / 128.0f) + 1e-6f);

    x1 = x1 * inv * (1.0f + scale[lane]);
    x2 = x2 * inv * (1.0f + scale[lane + 64]);

    const int   pos = segpos[bt];
    const float ts  = powf(10000.0f, (float)lane * (1.0f / 64.0f));
    const float ang = (float)pos / ts;
    const float sn = sinf(ang), cs = cosf(ang);

    float o1 = x1 * cs - x2 * sn;
    float o2 = x2 * cs + x1 * sn;
    if (!isK) {                       // rsqrt(128) * log2(e)
        o1 *= 0.1275174396f;
        o2 *= 0.1275174396f;
    }
    p[lane]      = f2b(o1);
    p[lane + 64] = f2b(o2);
}

// ---------------------------------------------------------------------------
// MFMA flash attention v3 (unchanged from round 10's measured 175 us).
// Block = (128-q tile, b*h), 512 thr = 8 waves, wave owns 16 q rows (M_rep=1).
// KVBLK=64. Linear LDS + XOR swizzle (byte ^= (row&7)<<4) for Ks/Vt/Pw.
// K staged via global_load_lds with pre-swizzled SOURCE (linear dest).
// Softmax in exp2 domain (q pre-scaled by log2e), defer-max THR=8.
// ---------------------------------------------------------------------------
__global__ __launch_bounds__(512, 4) void flash_kernel(const ushort* __restrict__ qkvb,
                                                       ushort* __restrict__ encb)
{
    __shared__ ushort Ks[64 * 128];      // [key][d]   16 KB, swizzled
    __shared__ ushort Vt[128 * 64];      // [d][key]   16 KB, swizzled
    __shared__ ushort Pw[8][16 * 64];    // per-wave P [q][key] 16 KB, swizzled

    const int tid = threadIdx.x;
    const int l   = tid & 63;
    const int w   = tid >> 6;            // wave 0..7
    const int l15 = l & 15, lg = l >> 4;
    const int bh  = blockIdx.y;
    const int b   = bh >> 4, h = bh & 15;
    const int q0  = blockIdx.x * 128;

    const ushort* Qg    = qkvb + (size_t)(b * TDIM + q0 + w * 16 + l15) * N3 + h * DDIM;
    const ushort* Kbase = qkvb + (size_t)(b * TDIM) * N3 +     CDIM + h * DDIM;
    const ushort* Vbase = qkvb + (size_t)(b * TDIM) * N3 + 2 * CDIM + h * DDIM;

    // Q fragments in registers (A-operand: row=l&15, k=(l>>4)*8+e)
    short8 qf[4];
    #pragma unroll
    for (int kk = 0; kk < 4; ++kk)
        qf[kk] = *(const short8*)(Qg + kk * 32 + lg * 8);

    f32x4 acc[8];
    #pragma unroll
    for (int n = 0; n < 8; ++n) acc[n] = (f32x4){0.f, 0.f, 0.f, 0.f};
    float mprev[4] = {-1e30f, -1e30f, -1e30f, -1e30f};
    float lrun[4]  = {0.f, 0.f, 0.f, 0.f};

    for (int kt = 0; kt < TDIM; kt += 64) {
        // ---- V: global -> regs (no LDS side effects, issue before barrier)
        short8 vreg[2];
        #pragma unroll
        for (int i = 0; i < 2; ++i)
            vreg[i] = *(const short8*)(Vbase + (size_t)(kt + l) * N3 + w * 16 + i * 8);
        __syncthreads();                              // prev tile readers done

        // ---- K: global_load_lds, linear dest + pre-swizzled source
        #pragma unroll
        for (int i = 0; i < 2; ++i) {
            const int c    = i * 512 + tid;           // 16B chunk id, 0..1023
            const int row  = c >> 4;                  // key row
            const int bsw  = (c & 15) << 4;           // dest byte within row
            const int bsrc = bsw ^ ((row & 7) << 4);  // source byte (involution)
            __builtin_amdgcn_global_load_lds(
                (const __attribute__((address_space(1))) unsigned int*)(Kbase + (size_t)(kt + row) * N3 + (bsrc >> 1)),
                (__attribute__((address_space(3))) unsigned int*)&Ks[c * 8], 16, 0, 0);
        }
        // ---- V: regs -> LDS transposed, swizzled scalar writes
        #pragma unroll
        for (int i = 0; i < 2; ++i) {
            #pragma unroll
            for (int j = 0; j < 8; ++j) {
                const int d = w * 16 + i * 8 + j;
                *(ushort*)((char*)Vt + d * 128 + (((l * 2) ^ ((d & 7) << 4)))) =
                    ((const ushort*)&vreg[i])[j];
            }
        }
        __syncthreads();                              // vmcnt drained by barrier

        // ---- S = Q K^T : 16q x 64k per wave (4 key-frags)
        f32x4 sf[4];
        #pragma unroll
        for (int n = 0; n < 4; ++n) sf[n] = (f32x4){0.f, 0.f, 0.f, 0.f};
        #pragma unroll
        for (int n = 0; n < 4; ++n) {
            const int key = n * 16 + l15;
            #pragma unroll
            for (int kk = 0; kk < 4; ++kk) {
                short8 kf = *(const short8*)((const char*)Ks + key * 256 +
                                             (((kk * 64 + lg * 16) ^ ((key & 7) << 4))));
                sf[n] = MFMA16(qf[kk], kf, sf[n]);
            }
        }

        // ---- online softmax (exp2 domain), defer-max THR=8
        #pragma unroll
        for (int r = 0; r < 4; ++r) {
            float rm = fmaxf(fmaxf(sf[0][r], sf[1][r]), fmaxf(sf[2][r], sf[3][r]));
            #pragma unroll
            for (int off = 8; off > 0; off >>= 1)
                rm = fmaxf(rm, __shfl_xor(rm, off, 16));
            if (rm > mprev[r] + 8.0f) {               // rescale only on real growth
                const float sc = exp2f(mprev[r] - rm);
                mprev[r] = rm;
                lrun[r] *= sc;
                #pragma unroll
                for (int n = 0; n < 8; ++n) acc[n][r] *= sc;
            }
            const float mn = mprev[r];
            float rs = 0.f;
            const int qr = lg * 4 + r;
            #pragma unroll
            for (int n = 0; n < 4; ++n) {
                const float pv = exp2f(sf[n][r] - mn);   // <= 2^8
                rs += pv;
                *(ushort*)((char*)&Pw[w][0] + qr * 128 +
                           ((n * 32 + l15 * 2) ^ ((qr & 7) << 4))) = f2b(pv);
            }
            #pragma unroll
            for (int off = 8; off > 0; off >>= 1) rs += __shfl_xor(rs, off, 16);
            lrun[r] += rs;
        }

        // ---- O += P V (P wave-local; no barrier needed)
        short8 pf[2];
        #pragma unroll
        for (int kk = 0; kk < 2; ++kk) {
            const int qr = l15;
            pf[kk] = *(const short8*)((const char*)&Pw[w][0] + qr * 128 +
                                      (((kk * 64 + lg * 16) ^ ((qr & 7) << 4))));
        }
        #pragma unroll
        for (int n = 0; n < 8; ++n) {
            const int d = n * 16 + l15;
            #pragma unroll
            for (int kk = 0; kk < 2; ++kk) {
                short8 vf = *(const short8*)((const char*)Vt + d * 128 +
                                             (((kk * 64 + lg * 16) ^ ((d & 7) << 4))));
                acc[n] = MFMA16(pf[kk], vf, acc[n]);
            }
        }
    }

    #pragma unroll
    for (int r = 0; r < 4; ++r) {
        const float inv = 1.0f / lrun[r];
        const size_t row = (size_t)(b * TDIM + q0 + w * 16 + lg * 4 + r);
        #pragma unroll
        for (int n = 0; n < 8; ++n)
            encb[row * CDIM + h * DDIM + n * 16 + l15] = f2b(acc[n][r] * inv);
    }
}

// ---------------------------------------------------------------------------
extern "C" void kernel_launch(void* const* d_in, const int* in_sizes, int n_in,
                              void* d_out, int out_size, void* d_ws, size_t ws_size,
                              hipStream_t stream)
{
    const float* x       = (const float*)d_in[0];
    const int*   segpos  = (const int*)  d_in[1];
    // d_in[2] = attn_mask (all true) -> unused
    const float* w_qkv   = (const float*)d_in[3];
    const float* w_out   = (const float*)d_in[4];
    const float* q_scale = (const float*)d_in[5];
    const float* k_scale = (const float*)d_in[6];
    float*       out     = (float*)d_out;

    // workspace layout (bf16 = ushort), total 112 MB
    ushort* x_b    = (ushort*)d_ws;                          // [4096][2048]
    ushort* wqkvT  = x_b   + (size_t)MDIM * CDIM;            // [6144][2048]
    ushort* woutT  = wqkvT + (size_t)N3   * CDIM;            // [2048][2048]
    ushort* qkv_b  = woutT + (size_t)CDIM * CDIM;            // [4096][6144]
    ushort* enc_b  = qkv_b + (size_t)MDIM * N3;              // [4096][2048]

    // 1) casts / weight transposes
    cast_bf16_kernel<<<dim3((MDIM * CDIM) / (256 * 8)), 256, 0, stream>>>(x, x_b, (size_t)MDIM * CDIM);
    transpose_cast_kernel<<<dim3(N3 / 32, CDIM / 32), 256, 0, stream>>>(w_qkv, wqkvT, CDIM, N3);
    transpose_cast_kernel<<<dim3(CDIM / 32, CDIM / 32), 256, 0, stream>>>(w_out, woutT, CDIM, CDIM);

    // 2) qkv = x @ w_qkv   (bf16 out) — 8-phase 256^2, grid 24x16
    gemm256_kernel<true><<<dim3(N3 / 256, MDIM / 256), 512, 0, stream>>>(x_b, wqkvT, qkv_b, N3, CDIM);

    // 3) RMSNorm + RoPE in place on q,k (q also picks up log2e)
    rmsrope_kernel<<<dim3(MDIM * 32 / 4), 256, 0, stream>>>(qkv_b, segpos, q_scale, k_scale);

    // 4) flash attention -> enc_b (bf16)
    flash_kernel<<<dim3(TDIM / 128, BDIM * HDIM), 512, 0, stream>>>(qkv_b, enc_b);

    // 5) out = enc @ w_out (fp32 out) — 8-phase 256^2, grid 8x16
    gemm256_kernel<false><<<dim3(CDIM / 256, MDIM / 256), 512, 0, stream>>>(enc_b, woutT, out, CDIM, CDIM);
}